// Round 3
// baseline (313.423 us; speedup 1.0000x reference)
//
#include <hip/hip_runtime.h>

#define DEV_INLINE __device__ __forceinline__

// Problem dims (fixed by setup_inputs)
constexpr int B = 16, T = 4096, C = 512, K = 3;
constexpr int G    = 128;        // segments per batch row
constexpr int Lseg = T / G;      // 32 steps per segment
constexpr int C4   = C / 4;      // 128 float4 lanes across channels
constexpr float EPS = 1e-4f;

// ws: gcarry[b][g][k][c4] float4  (B*G*K*C floats = 12.6 MB)

DEV_INLINE float4 f4mul(float4 a, float4 b) {
  return make_float4(a.x * b.x, a.y * b.y, a.z * b.z, a.w * b.w);
}
DEV_INLINE float4 f4fma(float4 a, float4 b, float4 c) {
  return make_float4(fmaf(a.x, b.x, c.x), fmaf(a.y, b.y, c.y),
                     fmaf(a.z, b.z, c.z), fmaf(a.w, b.w, c.w));
}
DEV_INLINE float4 f4onesub(float4 a) {
  return make_float4(1.f - a.x, 1.f - a.y, 1.f - a.z, 1.f - a.w);
}
DEV_INLINE float4 f4zero() { return make_float4(0.f, 0.f, 0.f, 0.f); }

DEV_INLINE float sig_clamp(float la) {
  float a = 1.0f / (1.0f + __expf(-la));
  return fminf(fmaxf(a, EPS), 1.0f - EPS);
}
DEV_INLINE float4 sig4(float4 la) {
  return make_float4(sig_clamp(la.x), sig_clamp(la.y), sig_clamp(la.z), sig_clamp(la.w));
}

// ---------------- K1: per-segment zero-init suffix ----------------
__global__ __launch_bounds__(128) void ema_k1(const float* __restrict__ x,
                                              const float* __restrict__ logit_alpha,
                                              float* __restrict__ ws) {
  const int c4 = threadIdx.x;          // 0..C4-1
  const int bi = blockIdx.x;           // b*G + g
  const int g  = bi & (G - 1);

  // coefficients inline (logit_alpha rows are C-contiguous -> float4 loads)
  const float4* laT = (const float4*)logit_alpha;
  const float4 a0 = sig4(laT[0 * C4 + c4]);
  const float4 a1 = sig4(laT[1 * C4 + c4]);
  const float4 a2 = sig4(laT[2 * C4 + c4]);
  const float4 b0 = f4onesub(a0), b1 = f4onesub(a1), b2 = f4onesub(a2);

  const float4* xb = (const float4*)x + (size_t)bi * Lseg * C4 + c4;

  float4 y0, y1, y2;
  int jstart;
  if (g == 0) {                        // exact init: y[0] = x[0]
    float4 x0 = xb[0];
    y0 = x0; y1 = x0; y2 = x0;
    jstart = 1;
  } else {
    y0 = f4zero(); y1 = y0; y2 = y0;
    jstart = 0;
  }

  #pragma unroll 4
  for (int j = jstart; j < Lseg; ++j) {
    float4 xv = xb[(size_t)j * C4];
    y0 = f4fma(a0, y0, f4mul(b0, xv));
    y1 = f4fma(a1, y1, f4mul(b1, xv));
    y2 = f4fma(a2, y2, f4mul(b2, xv));
  }

  float4* gc = (float4*)ws;
  const size_t cb = (size_t)bi * K * C4 + c4;
  gc[cb + 0 * C4] = y0;
  gc[cb + 1 * C4] = y1;
  gc[cb + 2 * C4] = y2;
}

// ---------------- K2: lookback over predecessor suffixes + recompute + mix ----------------
__global__ __launch_bounds__(128) void ema_k2(const float* __restrict__ x,
                                              const float* __restrict__ logit_alpha,
                                              const float* __restrict__ mix_logits,
                                              const float* __restrict__ ws,
                                              float* __restrict__ out) {
  const int c4 = threadIdx.x;
  const int bi = blockIdx.x;           // b*G + g
  const int g  = bi & (G - 1);
  const int b  = bi >> 7;              // G = 128

  const float4* laT = (const float4*)logit_alpha;
  const float4 a0 = sig4(laT[0 * C4 + c4]);
  const float4 a1 = sig4(laT[1 * C4 + c4]);
  const float4 a2 = sig4(laT[2 * C4 + c4]);
  const float4 b0 = f4onesub(a0), b1 = f4onesub(a1), b2 = f4onesub(a2);

  // softmax mix for this lane's 4 channels (mix_logits is [C][K])
  float mm0[4], mm1[4], mm2[4];
  #pragma unroll
  for (int u = 0; u < 4; ++u) {
    const int c = 4 * c4 + u;
    float l0 = mix_logits[c * K + 0];
    float l1 = mix_logits[c * K + 1];
    float l2 = mix_logits[c * K + 2];
    float mx = fmaxf(l0, fmaxf(l1, l2));
    float e0 = __expf(l0 - mx), e1 = __expf(l1 - mx), e2 = __expf(l2 - mx);
    float inv = 1.0f / (e0 + e1 + e2);
    mm0[u] = e0 * inv; mm1[u] = e1 * inv; mm2[u] = e2 * inv;
  }
  const float4 m0 = make_float4(mm0[0], mm0[1], mm0[2], mm0[3]);
  const float4 m1 = make_float4(mm1[0], mm1[1], mm1[2], mm1[3]);
  const float4 m2 = make_float4(mm2[0], mm2[1], mm2[2], mm2[3]);

  // A = a^Lseg = a^32 via 5 squarings
  float4 A0 = a0, A1 = a1, A2 = a2;
  #pragma unroll
  for (int s = 0; s < 5; ++s) { A0 = f4mul(A0, A0); A1 = f4mul(A1, A1); A2 = f4mul(A2, A2); }

  // lookback: S = sum_{g'<g} A^(g-1-g') * suffix[b][g']   (forward fold)
  float4 S0 = f4zero(), S1 = S0, S2 = S0;
  {
    const float4* gc = (const float4*)ws;
    size_t slot = ((size_t)b * G) * K * C4 + c4;
    for (int gp = 0; gp < g; ++gp) {        // g is block-uniform: no divergence
      float4 t0 = gc[slot + 0 * C4];
      float4 t1 = gc[slot + 1 * C4];
      float4 t2 = gc[slot + 2 * C4];
      S0 = f4fma(A0, S0, t0);
      S1 = f4fma(A1, S1, t1);
      S2 = f4fma(A2, S2, t2);
      slot += (size_t)K * C4;
    }
  }

  const float4* xb = (const float4*)x + (size_t)bi * Lseg * C4 + c4;
  float4*       ob = (float4*)out     + (size_t)bi * Lseg * C4 + c4;

  float4 y0, y1, y2;
  int jstart;
  if (g == 0) {
    float4 x0 = xb[0];
    y0 = x0; y1 = x0; y2 = x0;
    ob[0] = f4fma(m0, y0, f4fma(m1, y1, f4mul(m2, y2)));
    jstart = 1;
  } else {
    y0 = S0; y1 = S1; y2 = S2;
    jstart = 0;
  }

  #pragma unroll 4
  for (int j = jstart; j < Lseg; ++j) {
    float4 xv = xb[(size_t)j * C4];
    y0 = f4fma(a0, y0, f4mul(b0, xv));
    y1 = f4fma(a1, y1, f4mul(b1, xv));
    y2 = f4fma(a2, y2, f4mul(b2, xv));
    ob[(size_t)j * C4] = f4fma(m0, y0, f4fma(m1, y1, f4mul(m2, y2)));
  }
}

extern "C" void kernel_launch(void* const* d_in, const int* in_sizes, int n_in,
                              void* d_out, int out_size, void* d_ws, size_t ws_size,
                              hipStream_t stream) {
  const float* x           = (const float*)d_in[0];
  const float* logit_alpha = (const float*)d_in[1];
  const float* mix_logits  = (const float*)d_in[2];
  float* out = (float*)d_out;
  float* ws  = (float*)d_ws;

  ema_k1<<<B * G, 128, 0, stream>>>(x, logit_alpha, ws);
  ema_k2<<<B * G, 128, 0, stream>>>(x, logit_alpha, mix_logits, ws, out);
}